// Round 1
// baseline (3662.310 us; speedup 1.0000x reference)
//
#include <hip/hip_runtime.h>

// Problem dims
#define BB 4096
#define DD 2048
#define CC 1000

// ---------------------------------------------------------------------------
// Common wave-level reductions.  These MUST be the single shared definition
// used by both stats_kernel and opt_kernel so that iteration-1 of the
// optimizer reproduces p_trg bitwise (the reference gets sign(0)=0 there).
// ---------------------------------------------------------------------------
__device__ __forceinline__ void wave_argmax(float& val, int& idx) {
#pragma unroll
  for (int off = 1; off < 64; off <<= 1) {
    float ov = __shfl_xor(val, off, 64);
    int oi = __shfl_xor(idx, off, 64);
    if (ov > val || (ov == val && oi < idx)) { val = ov; idx = oi; }
  }
}

__device__ __forceinline__ float wave_sum(float v) {
#pragma unroll
  for (int off = 1; off < 64; off <<= 1) v += __shfl_xor(v, off, 64);
  return v;
}

// ---------------------------------------------------------------------------
// GEMM: Z = X @ W + b   (fp32, 64x64 tile, BK=16, 4x4 per thread)
// ---------------------------------------------------------------------------
__global__ __launch_bounds__(256) void gemm_kernel(
    const float* __restrict__ X, const float* __restrict__ W,
    const float* __restrict__ Bv, float* __restrict__ Z) {
  __shared__ float sA[16][68];
  __shared__ float sB[16][68];
  const int tid = threadIdx.x;
  const int rowTile = blockIdx.y * 64;
  const int colTile = blockIdx.x * 64;
  const int tx = tid & 15, ty = tid >> 4;
  float acc[4][4] = {};

  const int aRow = tid >> 2;        // 0..63
  const int aK = (tid & 3) << 2;    // 0,4,8,12
  const int bK = tid >> 4;          // 0..15
  const int bC = (tid & 15) << 2;   // 0..60
  const bool fullCol = (colTile + 64) <= CC;

  for (int k0 = 0; k0 < DD; k0 += 16) {
    const float4 av = *(const float4*)&X[(size_t)(rowTile + aRow) * DD + k0 + aK];
    sA[aK + 0][aRow] = av.x;
    sA[aK + 1][aRow] = av.y;
    sA[aK + 2][aRow] = av.z;
    sA[aK + 3][aRow] = av.w;
    float4 bv;
    if (fullCol) {
      bv = *(const float4*)&W[(size_t)(k0 + bK) * CC + colTile + bC];
    } else {
      const int c0 = colTile + bC;
      bv.x = (c0 + 0 < CC) ? W[(size_t)(k0 + bK) * CC + c0 + 0] : 0.f;
      bv.y = (c0 + 1 < CC) ? W[(size_t)(k0 + bK) * CC + c0 + 1] : 0.f;
      bv.z = (c0 + 2 < CC) ? W[(size_t)(k0 + bK) * CC + c0 + 2] : 0.f;
      bv.w = (c0 + 3 < CC) ? W[(size_t)(k0 + bK) * CC + c0 + 3] : 0.f;
    }
    *(float4*)&sB[bK][bC] = bv;
    __syncthreads();
#pragma unroll
    for (int kk = 0; kk < 16; ++kk) {
      const float4 a4 = *(const float4*)&sA[kk][ty << 2];
      const float4 b4 = *(const float4*)&sB[kk][tx << 2];
      const float ar[4] = {a4.x, a4.y, a4.z, a4.w};
      const float br[4] = {b4.x, b4.y, b4.z, b4.w};
#pragma unroll
      for (int i = 0; i < 4; ++i)
#pragma unroll
        for (int j = 0; j < 4; ++j) acc[i][j] = fmaf(ar[i], br[j], acc[i][j]);
    }
    __syncthreads();
  }
#pragma unroll
  for (int i = 0; i < 4; ++i) {
    const int r = rowTile + (ty << 2) + i;
#pragma unroll
    for (int j = 0; j < 4; ++j) {
      const int c = colTile + (tx << 2) + j;
      if (c < CC) Z[(size_t)r * CC + c] = acc[i][j] + Bv[c];
    }
  }
}

// ---------------------------------------------------------------------------
// Per-row stats from z: y = argmax, l_trg, p_trg.
// One wave per row; lane l owns columns l + 64*k, k = 0..15.
// ---------------------------------------------------------------------------
__global__ __launch_bounds__(256) void stats_kernel(
    const float* __restrict__ Z, int* __restrict__ Y,
    float* __restrict__ Lt, float* __restrict__ Pt) {
  const int wave = threadIdx.x >> 6, lane = threadIdx.x & 63;
  const int row = blockIdx.x * 4 + wave;
  float uv[16];
#pragma unroll
  for (int k = 0; k < 16; ++k) {
    const int j = lane + (k << 6);
    uv[k] = (j < CC) ? Z[(size_t)row * CC + j] : -__builtin_inff();
  }
  float mx = uv[0];
  int ai = lane;
#pragma unroll
  for (int k = 1; k < 16; ++k) {
    const int j = lane + (k << 6);
    if (uv[k] > mx) { mx = uv[k]; ai = j; }
  }
  wave_argmax(mx, ai);
  float sum = 0.f;
#pragma unroll
  for (int k = 0; k < 16; ++k) sum += expf(uv[k] - mx);
  sum = wave_sum(sum);
  if (lane == 0) {
    const float lse = mx + logf(sum);
    const float lorg = lse - mx;  // == lse - z[y]
    const float latr = (floorf(lorg / 6.0f) + 0.5f) * 6.0f;
    const float lt =
        lorg - 6.0f * sinf(3.14159265358979323846f *
                           (1.0f - 2.0f * (lorg - latr) / 6.0f));
    Y[row] = ai;
    Lt[row] = lt;
    Pt[row] = 1.0f / sum;  // max softmax = exp(max - lse) = 1/sum
  }
}

// ---------------------------------------------------------------------------
// Bitonic sort of p_trg (4096) in LDS, single block. Also zeroes the barrier
// counter (d_ws is re-poisoned 0xAA before every launch).
// ---------------------------------------------------------------------------
__global__ __launch_bounds__(1024) void sort_kernel(
    const float* __restrict__ P, float* __restrict__ Out,
    unsigned int* __restrict__ Cnt) {
  __shared__ float s[4096];
  const int tid = threadIdx.x;
  if (tid == 0) *Cnt = 0u;
  for (int i = tid; i < 4096; i += 1024) s[i] = P[i];
  __syncthreads();
  for (int k = 2; k <= 4096; k <<= 1) {
    for (int j = k >> 1; j > 0; j >>= 1) {
      for (int i = tid; i < 4096; i += 1024) {
        const int ixj = i ^ j;
        if (ixj > i) {
          const float a = s[i], b = s[ixj];
          const bool up = ((i & k) == 0);
          if (up ? (a > b) : (a < b)) { s[i] = b; s[ixj] = a; }
        }
      }
      __syncthreads();
    }
  }
  for (int i = tid; i < 4096; i += 1024) Out[i] = s[i];
}

// ---------------------------------------------------------------------------
// Cooperative optimizer: 256 blocks x 1024 threads, 1 block/CU.
// One wave per row; u,m,v live in registers for all 100 iterations.
// Per iteration: one custom device-scope grid barrier.
// ---------------------------------------------------------------------------
__global__ __launch_bounds__(1024, 4) void opt_kernel(
    float* __restrict__ ZU, const int* __restrict__ Yarr,
    const float* __restrict__ Ltrg, const float* __restrict__ Sorted,
    unsigned long long* __restrict__ Slots, unsigned int* __restrict__ Cnt) {
  const int tid = threadIdx.x;
  const int wave = tid >> 6, lane = tid & 63;
  const int row = blockIdx.x * 16 + wave;

  __shared__ float s_sorted[4096];
  __shared__ float s_cval[16];
  __shared__ int s_cidx[16];
  __shared__ float s_bcf[2];  // sstar, S
  __shared__ int s_bci[2];    // rstar, cstar

  for (int i = tid; i < 4096; i += 1024) s_sorted[i] = Sorted[i];

  float u[16], m[16], v[16];
#pragma unroll
  for (int k = 0; k < 16; ++k) {
    const int j = lane + (k << 6);
    u[k] = (j < CC) ? ZU[(size_t)row * CC + j] : -__builtin_inff();
    m[k] = 0.f;
    v[k] = 0.f;
  }
  const int y = Yarr[row];
  const float ltrg = Ltrg[row];
  const int ky = y >> 6, ly = y & 63;

  float pb1 = 1.0f, pb2 = 1.0f;
  __syncthreads();

#pragma unroll 1
  for (int t = 1; t <= 100; ++t) {
    pb1 *= 0.9f;
    pb2 *= 0.999f;
    const float im1 = 1.0f / (1.0f - pb1);
    const float im2 = 1.0f / (1.0f - pb2);

    // ---- Phase A: row stats (identical arithmetic to stats_kernel) ----
    float mx = u[0];
    int ai = lane;
#pragma unroll
    for (int k = 1; k < 16; ++k) {
      const int j = lane + (k << 6);
      if (u[k] > mx) { mx = u[k]; ai = j; }
    }
    wave_argmax(mx, ai);
    float sum = 0.f;
#pragma unroll
    for (int k = 0; k < 16; ++k) sum += expf(u[k] - mx);
    sum = wave_sum(sum);
    const float lse = mx + logf(sum);
    float uyl = 0.f;
#pragma unroll
    for (int k = 0; k < 16; ++k) uyl = (k == ky) ? u[k] : uyl;
    const float uy = __shfl(uyl, ly, 64);
    const float ce = lse - uy;
    const float pmax = 1.0f / sum;  // row max softmax

    if (lane == 0) {
      s_cval[wave] = pmax;
      s_cidx[wave] = (row << 10) | ai;
    }
    __syncthreads();
    if (tid == 0) {
      float bv = s_cval[0];
      int bi = s_cidx[0];
#pragma unroll
      for (int w = 1; w < 16; ++w) {
        const float ov = s_cval[w];
        const int oi = s_cidx[w];
        if (ov > bv || (ov == bv && oi < bi)) { bv = ov; bi = oi; }
      }
      const unsigned long long pack =
          ((unsigned long long)__float_as_uint(bv) << 32) | (unsigned)bi;
      __hip_atomic_store(&Slots[(t & 1) * 256 + blockIdx.x], pack,
                         __ATOMIC_RELEASE, __HIP_MEMORY_SCOPE_AGENT);
    }
    __syncthreads();

    // ---- grid barrier (monotone counter; Cnt zeroed by sort_kernel) ----
    if (tid == 0) {
      __hip_atomic_fetch_add(Cnt, 1u, __ATOMIC_RELEASE,
                             __HIP_MEMORY_SCOPE_AGENT);
      const unsigned target = (unsigned)t * 256u;
      while (__hip_atomic_load(Cnt, __ATOMIC_ACQUIRE,
                               __HIP_MEMORY_SCOPE_AGENT) < target)
        __builtin_amdgcn_s_sleep(1);
    }
    __syncthreads();

    // ---- Phase B: global argmax over 256 slots + rank query for S ----
    if (wave == 0) {
      float bv = -1.0f;
      int bi = 0x7fffffff;
#pragma unroll
      for (int q = 0; q < 4; ++q) {
        const unsigned long long p = __hip_atomic_load(
            &Slots[(t & 1) * 256 + lane + (q << 6)], __ATOMIC_ACQUIRE,
            __HIP_MEMORY_SCOPE_AGENT);
        const float ov = __uint_as_float((unsigned)(p >> 32));
        const int oi = (int)(p & 0xffffffffu);
        if (ov > bv || (ov == bv && oi < bi)) { bv = ov; bi = oi; }
      }
      wave_argmax(bv, bi);
      const float ss = bv;
      // rank queries on sorted p_trg: S = #(p_trg < ss) - #(p_trg > ss)
      const float v1 = s_sorted[lane << 6];
      const int c1 = __popcll(__ballot(v1 < ss));
      int nlt = 0;
      if (c1 > 0) {
        const float v2 = s_sorted[((c1 - 1) << 6) + lane];
        nlt = ((c1 - 1) << 6) + __popcll(__ballot(v2 < ss));
      }
      const int c2 = __popcll(__ballot(v1 <= ss));
      int nle = 0;
      if (c2 > 0) {
        const float v3 = s_sorted[((c2 - 1) << 6) + lane];
        nle = ((c2 - 1) << 6) + __popcll(__ballot(v3 <= ss));
      }
      const int S = nlt - (4096 - nle);
      if (lane == 0) {
        s_bcf[0] = ss;
        s_bcf[1] = (float)S;
        s_bci[0] = bi >> 10;
        s_bci[1] = bi & 1023;
      }
    }
    __syncthreads();
    const float sstar = s_bcf[0];
    const float coef = 5.0f * s_bcf[1] * sstar;  // BETA * S * M
    const bool isr = (row == s_bci[0]);
    const int cstar = s_bci[1];
    const float a = (ce > ltrg) ? 1.0f : ((ce < ltrg) ? -1.0f : 0.0f);

    // ---- gradient + AdamW (ref order: decay u, then m/v, then step) ----
#pragma unroll
    for (int k = 0; k < 16; ++k) {
      const int j = lane + (k << 6);
      const float p = expf(u[k] - lse);  // softmax(u)[j]
      float g = a * (p - ((j == y) ? 1.0f : 0.0f));
      if (isr) g += coef * (((j == cstar) ? 1.0f : 0.0f) - p);
      u[k] *= 0.999f;  // 1 - LR*WD
      m[k] = 0.9f * m[k] + 0.1f * g;
      v[k] = 0.999f * v[k] + 0.001f * g * g;
      const float mh = m[k] * im1;
      const float vh = v[k] * im2;
      u[k] -= (0.1f * mh) / (sqrtf(vh) + 1e-8f);
    }
  }

#pragma unroll
  for (int k = 0; k < 16; ++k) {
    const int j = lane + (k << 6);
    if (j < CC) ZU[(size_t)row * CC + j] = u[k];
  }
}

// ---------------------------------------------------------------------------
extern "C" void kernel_launch(void* const* d_in, const int* in_sizes, int n_in,
                              void* d_out, int out_size, void* d_ws,
                              size_t ws_size, hipStream_t stream) {
  const float* x = (const float*)d_in[0];
  const float* W = (const float*)d_in[1];
  const float* b = (const float*)d_in[2];
  float* z = (float*)d_out;  // z lives in d_out; overwritten with u at the end

  char* ws = (char*)d_ws;
  int* y_arr = (int*)ws;                              // 16 KB
  float* ltrg_arr = (float*)(ws + (16 << 10));        // 16 KB
  float* ptrg_arr = (float*)(ws + (32 << 10));        // 16 KB
  float* sorted = (float*)(ws + (48 << 10));          // 16 KB
  unsigned long long* slots =
      (unsigned long long*)(ws + (64 << 10));         // 4 KB (2 x 256)
  unsigned int* cnt = (unsigned int*)(ws + (72 << 10));

  gemm_kernel<<<dim3(16, 64), 256, 0, stream>>>(x, W, b, z);
  stats_kernel<<<dim3(1024), 256, 0, stream>>>(z, y_arr, ltrg_arr, ptrg_arr);
  sort_kernel<<<dim3(1), 1024, 0, stream>>>(ptrg_arr, sorted, cnt);

  void* args[6] = {&z, &y_arr, &ltrg_arr, &sorted, &slots, &cnt};
  hipLaunchCooperativeKernel((const void*)opt_kernel, dim3(256), dim3(1024),
                             args, 0u, stream);
}

// Round 2
// 2472.803 us; speedup vs baseline: 1.4810x; 1.4810x over previous
//
#include <hip/hip_runtime.h>

// Problem dims
#define BB 4096
#define DD 2048
#define CC 1000

// ---------------------------------------------------------------------------
// Common wave-level reductions.  Single shared definition used by both
// stats_kernel and opt_kernel so iteration-1 of the optimizer reproduces
// p_trg bitwise (the reference gets sign(0)=0 there).
// ---------------------------------------------------------------------------
__device__ __forceinline__ void wave_argmax(float& val, int& idx) {
#pragma unroll
  for (int off = 1; off < 64; off <<= 1) {
    float ov = __shfl_xor(val, off, 64);
    int oi = __shfl_xor(idx, off, 64);
    if (ov > val || (ov == val && oi < idx)) { val = ov; idx = oi; }
  }
}

__device__ __forceinline__ float wave_sum(float v) {
#pragma unroll
  for (int off = 1; off < 64; off <<= 1) v += __shfl_xor(v, off, 64);
  return v;
}

// ---------------------------------------------------------------------------
// GEMM: Z = X @ W + b   (fp32, 64x64 tile, BK=16, 4x4 per thread)
// ---------------------------------------------------------------------------
__global__ __launch_bounds__(256) void gemm_kernel(
    const float* __restrict__ X, const float* __restrict__ W,
    const float* __restrict__ Bv, float* __restrict__ Z) {
  __shared__ float sA[16][68];
  __shared__ float sB[16][68];
  const int tid = threadIdx.x;
  const int rowTile = blockIdx.y * 64;
  const int colTile = blockIdx.x * 64;
  const int tx = tid & 15, ty = tid >> 4;
  float acc[4][4] = {};

  const int aRow = tid >> 2;        // 0..63
  const int aK = (tid & 3) << 2;    // 0,4,8,12
  const int bK = tid >> 4;          // 0..15
  const int bC = (tid & 15) << 2;   // 0..60
  const bool fullCol = (colTile + 64) <= CC;

  for (int k0 = 0; k0 < DD; k0 += 16) {
    const float4 av = *(const float4*)&X[(size_t)(rowTile + aRow) * DD + k0 + aK];
    sA[aK + 0][aRow] = av.x;
    sA[aK + 1][aRow] = av.y;
    sA[aK + 2][aRow] = av.z;
    sA[aK + 3][aRow] = av.w;
    float4 bv;
    if (fullCol) {
      bv = *(const float4*)&W[(size_t)(k0 + bK) * CC + colTile + bC];
    } else {
      const int c0 = colTile + bC;
      bv.x = (c0 + 0 < CC) ? W[(size_t)(k0 + bK) * CC + c0 + 0] : 0.f;
      bv.y = (c0 + 1 < CC) ? W[(size_t)(k0 + bK) * CC + c0 + 1] : 0.f;
      bv.z = (c0 + 2 < CC) ? W[(size_t)(k0 + bK) * CC + c0 + 2] : 0.f;
      bv.w = (c0 + 3 < CC) ? W[(size_t)(k0 + bK) * CC + c0 + 3] : 0.f;
    }
    *(float4*)&sB[bK][bC] = bv;
    __syncthreads();
#pragma unroll
    for (int kk = 0; kk < 16; ++kk) {
      const float4 a4 = *(const float4*)&sA[kk][ty << 2];
      const float4 b4 = *(const float4*)&sB[kk][tx << 2];
      const float ar[4] = {a4.x, a4.y, a4.z, a4.w};
      const float br[4] = {b4.x, b4.y, b4.z, b4.w};
#pragma unroll
      for (int i = 0; i < 4; ++i)
#pragma unroll
        for (int j = 0; j < 4; ++j) acc[i][j] = fmaf(ar[i], br[j], acc[i][j]);
    }
    __syncthreads();
  }
#pragma unroll
  for (int i = 0; i < 4; ++i) {
    const int r = rowTile + (ty << 2) + i;
#pragma unroll
    for (int j = 0; j < 4; ++j) {
      const int c = colTile + (tx << 2) + j;
      if (c < CC) Z[(size_t)r * CC + c] = acc[i][j] + Bv[c];
    }
  }
}

// ---------------------------------------------------------------------------
// Per-row stats from z: y = argmax, l_trg, p_trg.
// One wave per row; lane l owns columns l + 64*k, k = 0..15.
// ---------------------------------------------------------------------------
__global__ __launch_bounds__(256) void stats_kernel(
    const float* __restrict__ Z, int* __restrict__ Y,
    float* __restrict__ Lt, float* __restrict__ Pt) {
  const int wave = threadIdx.x >> 6, lane = threadIdx.x & 63;
  const int row = blockIdx.x * 4 + wave;
  float uv[16];
#pragma unroll
  for (int k = 0; k < 16; ++k) {
    const int j = lane + (k << 6);
    uv[k] = (j < CC) ? Z[(size_t)row * CC + j] : -__builtin_inff();
  }
  float mx = uv[0];
  int ai = lane;
#pragma unroll
  for (int k = 1; k < 16; ++k) {
    const int j = lane + (k << 6);
    if (uv[k] > mx) { mx = uv[k]; ai = j; }
  }
  wave_argmax(mx, ai);
  float sum = 0.f;
#pragma unroll
  for (int k = 0; k < 16; ++k) sum += expf(uv[k] - mx);
  sum = wave_sum(sum);
  if (lane == 0) {
    const float lse = mx + logf(sum);
    const float lorg = lse - mx;  // == lse - z[y]
    const float latr = (floorf(lorg / 6.0f) + 0.5f) * 6.0f;
    const float lt =
        lorg - 6.0f * sinf(3.14159265358979323846f *
                           (1.0f - 2.0f * (lorg - latr) / 6.0f));
    Y[row] = ai;
    Lt[row] = lt;
    Pt[row] = 1.0f / sum;  // max softmax = exp(max - lse) = 1/sum
  }
}

// ---------------------------------------------------------------------------
// Bitonic sort of p_trg (4096) in LDS, single block.
// ---------------------------------------------------------------------------
__global__ __launch_bounds__(1024) void sort_kernel(
    const float* __restrict__ P, float* __restrict__ Out) {
  __shared__ float s[4096];
  const int tid = threadIdx.x;
  for (int i = tid; i < 4096; i += 1024) s[i] = P[i];
  __syncthreads();
  for (int k = 2; k <= 4096; k <<= 1) {
    for (int j = k >> 1; j > 0; j >>= 1) {
      for (int i = tid; i < 4096; i += 1024) {
        const int ixj = i ^ j;
        if (ixj > i) {
          const float a = s[i], b = s[ixj];
          const bool up = ((i & k) == 0);
          if (up ? (a > b) : (a < b)) { s[i] = b; s[ixj] = a; }
        }
      }
      __syncthreads();
    }
  }
  for (int i = tid; i < 4096; i += 1024) Out[i] = s[i];
}

// ---------------------------------------------------------------------------
// Cooperative optimizer: 256 blocks x 1024 threads, 1 block/CU.
// One wave per row; u,m,v (and cached exp) live in registers for all 100
// iterations.  Global sync per iteration = ONE visibility hop:
//   - each block release-stores one epoch-tagged 64-bit candidate slot
//     {pmax_bits:32 | epoch:8 | (row:12,col:10):22} (parity double-buffered)
//   - every block's wave 0 polls all 256 slots until epoch==t, then computes
//     the global argmax + rank-query S locally (sorted p_trg is in LDS).
// No counter, no RMW, no second broadcast hop.  Safety: a slot of epoch t is
// only overwritten (epoch t+2, same parity) after every block wrote epoch
// t+1, which happens after every block exited the epoch-t poll.
// ---------------------------------------------------------------------------
__global__ __launch_bounds__(1024, 4) void opt_kernel(
    float* __restrict__ ZU, const int* __restrict__ Yarr,
    const float* __restrict__ Ltrg, const float* __restrict__ Sorted,
    unsigned long long* __restrict__ Slots) {
  const int tid = threadIdx.x;
  const int wave = tid >> 6, lane = tid & 63;
  const int row = blockIdx.x * 16 + wave;

  __shared__ float s_sorted[4096];
  __shared__ float s_cval[16];
  __shared__ int s_cidx[16];
  __shared__ float s_coef;
  __shared__ int s_rc;  // rstar<<10 | cstar

  for (int i = tid; i < 4096; i += 1024) s_sorted[i] = Sorted[i];

  float u[16], m[16], v[16], e[16];
#pragma unroll
  for (int k = 0; k < 16; ++k) {
    const int j = lane + (k << 6);
    u[k] = (j < CC) ? ZU[(size_t)row * CC + j] : -__builtin_inff();
    m[k] = 0.f;
    v[k] = 0.f;
  }
  const int y = Yarr[row];
  const float ltrg = Ltrg[row];
  const int ky = y >> 6, ly = y & 63;

  float pb1 = 1.0f, pb2 = 1.0f;
  __syncthreads();

#pragma unroll 1
  for (int t = 1; t <= 100; ++t) {
    pb1 *= 0.9f;
    pb2 *= 0.999f;
    const float im1 = 1.0f / (1.0f - pb1);
    const float im2 = 1.0f / (1.0f - pb2);

    // ---- Phase A: row stats (same arithmetic as stats_kernel) ----
    float mx = u[0];
    int ai = lane;
#pragma unroll
    for (int k = 1; k < 16; ++k) {
      const int j = lane + (k << 6);
      if (u[k] > mx) { mx = u[k]; ai = j; }
    }
    wave_argmax(mx, ai);
    float sum = 0.f;
#pragma unroll
    for (int k = 0; k < 16; ++k) {
      e[k] = expf(u[k] - mx);
      sum += e[k];
    }
    sum = wave_sum(sum);
    const float lse = mx + logf(sum);
    float uyl = 0.f;
#pragma unroll
    for (int k = 0; k < 16; ++k) uyl = (k == ky) ? u[k] : uyl;
    const float uy = __shfl(uyl, ly, 64);
    const float ce = lse - uy;
    const float pmax = 1.0f / sum;  // row max softmax

    if (lane == 0) {
      s_cval[wave] = pmax;
      s_cidx[wave] = (row << 10) | ai;
    }
    __syncthreads();

    unsigned long long* slot_buf = &Slots[(t & 1) * 256];
    if (tid == 0) {
      float bv = s_cval[0];
      int bi = s_cidx[0];
#pragma unroll
      for (int w = 1; w < 16; ++w) {
        const float ov = s_cval[w];
        const int oi = s_cidx[w];
        if (ov > bv || (ov == bv && oi < bi)) { bv = ov; bi = oi; }
      }
      const unsigned long long pack =
          ((unsigned long long)__float_as_uint(bv) << 32) |
          (unsigned)((t << 24) | bi);
      __hip_atomic_store(&slot_buf[blockIdx.x], pack, __ATOMIC_RELEASE,
                         __HIP_MEMORY_SCOPE_AGENT);
    }

    // ---- wave 0: poll all 256 slots, then global argmax + rank-query S ----
    if (wave == 0) {
      unsigned long long pv[4];
      unsigned fresh = 0u;
      while (fresh != 0xFu) {
#pragma unroll
        for (int q = 0; q < 4; ++q) {
          if (!(fresh & (1u << q))) {
            const unsigned long long p = __hip_atomic_load(
                &slot_buf[lane + (q << 6)], __ATOMIC_ACQUIRE,
                __HIP_MEMORY_SCOPE_AGENT);
            if ((unsigned)((p >> 24) & 0xFFu) == (unsigned)t) {
              pv[q] = p;
              fresh |= 1u << q;
            }
          }
        }
        if (fresh != 0xFu) __builtin_amdgcn_s_sleep(2);
      }
      float bv = -1.0f;
      int bi = 0x7fffffff;
#pragma unroll
      for (int q = 0; q < 4; ++q) {
        const float ov = __uint_as_float((unsigned)(pv[q] >> 32));
        const int oi = (int)(pv[q] & 0x3FFFFFu);
        if (ov > bv || (ov == bv && oi < bi)) { bv = ov; bi = oi; }
      }
      wave_argmax(bv, bi);
      const float ss = bv;
      // rank queries on sorted p_trg: S = #(p_trg < ss) - #(p_trg > ss)
      const float v1 = s_sorted[lane << 6];
      const int c1 = __popcll(__ballot(v1 < ss));
      int nlt = 0;
      if (c1 > 0) {
        const float v2 = s_sorted[((c1 - 1) << 6) + lane];
        nlt = ((c1 - 1) << 6) + __popcll(__ballot(v2 < ss));
      }
      const int c2 = __popcll(__ballot(v1 <= ss));
      int nle = 0;
      if (c2 > 0) {
        const float v3 = s_sorted[((c2 - 1) << 6) + lane];
        nle = ((c2 - 1) << 6) + __popcll(__ballot(v3 <= ss));
      }
      const int S = nlt - (4096 - nle);
      if (lane == 0) {
        s_coef = 5.0f * (float)S * ss;  // BETA * S * M
        s_rc = bi;
      }
    }
    __syncthreads();

    const float coef = s_coef;
    const int rc = s_rc;
    const bool isr = (row == (rc >> 10));
    const int cstar = rc & 1023;
    const float a = (ce > ltrg) ? 1.0f : ((ce < ltrg) ? -1.0f : 0.0f);

    // ---- gradient + AdamW (ref order: decay u, then m/v, then step) ----
#pragma unroll
    for (int k = 0; k < 16; ++k) {
      const int j = lane + (k << 6);
      const float p = e[k] * pmax;  // softmax(u)[j] = exp(u-mx)/sum
      float g = a * (p - ((j == y) ? 1.0f : 0.0f));
      if (isr) g += coef * (((j == cstar) ? 1.0f : 0.0f) - p);
      u[k] *= 0.999f;  // 1 - LR*WD
      m[k] = 0.9f * m[k] + 0.1f * g;
      v[k] = 0.999f * v[k] + 0.001f * g * g;
      const float mh = m[k] * im1;
      const float vh = v[k] * im2;
      u[k] -= (0.1f * mh) / (sqrtf(vh) + 1e-8f);
    }
  }

#pragma unroll
  for (int k = 0; k < 16; ++k) {
    const int j = lane + (k << 6);
    if (j < CC) ZU[(size_t)row * CC + j] = u[k];
  }
}

// ---------------------------------------------------------------------------
extern "C" void kernel_launch(void* const* d_in, const int* in_sizes, int n_in,
                              void* d_out, int out_size, void* d_ws,
                              size_t ws_size, hipStream_t stream) {
  const float* x = (const float*)d_in[0];
  const float* W = (const float*)d_in[1];
  const float* b = (const float*)d_in[2];
  float* z = (float*)d_out;  // z lives in d_out; overwritten with u at the end

  char* ws = (char*)d_ws;
  int* y_arr = (int*)ws;                              // 16 KB
  float* ltrg_arr = (float*)(ws + (16 << 10));        // 16 KB
  float* ptrg_arr = (float*)(ws + (32 << 10));        // 16 KB
  float* sorted = (float*)(ws + (48 << 10));          // 16 KB
  unsigned long long* slots =
      (unsigned long long*)(ws + (64 << 10));         // 4 KB (2 x 256)

  gemm_kernel<<<dim3(16, 64), 256, 0, stream>>>(x, W, b, z);
  stats_kernel<<<dim3(1024), 256, 0, stream>>>(z, y_arr, ltrg_arr, ptrg_arr);
  sort_kernel<<<dim3(1), 1024, 0, stream>>>(ptrg_arr, sorted);

  void* args[5] = {&z, &y_arr, &ltrg_arr, &sorted, &slots};
  hipLaunchCooperativeKernel((const void*)opt_kernel, dim3(256), dim3(1024),
                             args, 0u, stream);
}